// Round 1
// baseline (926.417 us; speedup 1.0000x reference)
//
#include <hip/hip_runtime.h>

#define N_NODES 100000
#define N_EDGES 1600000
#define N_GRAPHS 256
#define F_IN 38
#define F_PAD 40    // x packed to 40 f16 (80 B rows = 20 uints)
#define HID 64
#define CAPD 48     // dst-CSR capacity (in-deg Poisson(16); 48 proven)

// edge partition parameters
#define NB   391    // buckets of 256 nodes: bucket = node >> 8
#define EPB  4096   // edges per chunk-block
#define NBLK 391    // ceil(N_EDGES / EPB)
#define BCAP 4608   // per-bucket ebuf capacity (mean 4096, +8 sigma)
#define P2   196    // layer2 accumulator blocks (bucket p and p+196 -> balanced)

typedef unsigned short ushort;
typedef unsigned int uint;
typedef _Float16 h2 __attribute__((ext_vector_type(2)));

__device__ __forceinline__ h2 u2h(uint u) {
    union { uint u; h2 h; } v; v.u = u; return v.h;
}
__device__ __forceinline__ uint h2u(h2 h) {
    union { uint u; h2 h; } v; v.h = h; return v.u;
}
__device__ __forceinline__ ushort f2h_bits(float f) {
    union { _Float16 h; ushort s; } v; v.h = (_Float16)f; return v.s;
}
// Defensive clamp: any out-of-range index maps to the all-zero dummy row N_NODES.
__device__ __forceinline__ int clampi(int v) {
    return (int)min((uint)v, (uint)N_NODES);
}

// ---------------------------------------------------------------------------
// Pack x [N][38] fp32 -> xb [N+1][40] f16 (zero cols 38..39; row N all-zero).
// Also zeroes the hb dummy row N.
// ---------------------------------------------------------------------------
__global__ void pack_x_kernel(const float* __restrict__ x,
                              ushort* __restrict__ xb,
                              ushort* __restrict__ hb) {
    int tid = blockIdx.x * blockDim.x + threadIdx.x;
    if (tid < HID) hb[(N_NODES << 6) + tid] = 0;
    if (tid >= (N_NODES + 1) * F_PAD) return;
    int n = tid / F_PAD;
    int f = tid - n * F_PAD;
    float v = (n < N_NODES && f < F_IN) ? x[n * F_IN + f] : 0.0f;
    xb[tid] = f2h_bits(v);
}

// ---------------------------------------------------------------------------
// Scatter edges into fixed-capacity dst-bucket regions of ebuf.
// Payload compressed to one uint: (src << 8) | (dst & 255)  (src < 2^17).
// ---------------------------------------------------------------------------
__global__ void scatter_kernel(const int* __restrict__ src,
                               const int* __restrict__ dst,
                               int* __restrict__ gcur,
                               uint* __restrict__ ebuf) {
    __shared__ int hist[NB];
    __shared__ int cur[NB];
    for (int i = threadIdx.x; i < NB; i += 256) hist[i] = 0;
    __syncthreads();
    const int base = blockIdx.x * EPB;
    int d[EPB / 256];
    uint pl[EPB / 256];
    #pragma unroll
    for (int i = 0; i < EPB / 256; ++i) {
        int e = base + i * 256 + threadIdx.x;
        d[i] = (e < N_EDGES) ? dst[e] : -1;
        if (d[i] >= 0) {
            pl[i] = ((uint)src[e] << 8) | ((uint)d[i] & 255u);
            atomicAdd(&hist[d[i] >> 8], 1);
        }
    }
    __syncthreads();
    for (int i = threadIdx.x; i < NB; i += 256) {
        int c = hist[i];
        cur[i] = (c > 0) ? atomicAdd(&gcur[i], c) : 0;
    }
    __syncthreads();
    #pragma unroll
    for (int i = 0; i < EPB / 256; ++i) {
        if (d[i] >= 0) {
            int b = d[i] >> 8;
            int pos = atomicAdd(&cur[b], 1);
            if (pos < BCAP) ebuf[b * BCAP + pos] = pl[i];
        }
    }
}

// ---------------------------------------------------------------------------
// One block per dst-bucket builds its 256 nodes' slot lists.
// NEW: explicitly fills the rounded-up tail [deg, dp) with the dummy row
// index N_NODES, so slot tails never depend on workspace poison (the slots
// region is reused by ebuf2/partial later in the same iteration).
// ---------------------------------------------------------------------------
__global__ void build_kernel(const uint* __restrict__ ebuf,
                             const int* __restrict__ gcur,
                             int* __restrict__ cnt,
                             int* __restrict__ slots) {
    __shared__ int cl[256];
    const int b = blockIdx.x;
    cl[threadIdx.x] = 0;
    __syncthreads();
    int e1 = gcur[b]; if (e1 > BCAP) e1 = BCAP;
    for (int idx = threadIdx.x; idx < e1; idx += 256) {
        uint e = ebuf[b * BCAP + idx];
        int dl = (int)(e & 255u);
        int pos = atomicAdd(&cl[dl], 1);
        if (pos < CAPD) slots[((b << 8) + dl) * CAPD + pos] = (int)(e >> 8);
    }
    __syncthreads();
    int n = (b << 8) + threadIdx.x;
    if (n < N_NODES) {
        int c = cl[threadIdx.x];
        cnt[n] = c;
        int d = (c > CAPD) ? CAPD : c;
        int dp = (d + 15) & ~15; if (dp > CAPD) dp = CAPD;
        for (int j = d; j < dp; ++j) slots[n * CAPD + j] = N_NODES;  // dummy row
    }
}

// ---------------------------------------------------------------------------
// Layer 1 fused (r17 Phase B, dual-node Phase A): lanes 0-31 gather the even
// node, lanes 32-63 the odd node (l32<20 active per half) -> 32 rows in
// flight per wave (2x MLP vs r17). Phase B = v_pk_fma vs pair-packed LDS
// weights, SINGLE h2 accumulator. LDS 20 KB. Keep launch_bounds(256,4).
// ---------------------------------------------------------------------------
__global__ __launch_bounds__(256, 4) void layer1_kernel(
        const uint* __restrict__ xb32,
        const int* __restrict__ cnt,
        const int* __restrict__ slots,
        const float* __restrict__ w_rel,
        const float* __restrict__ b_rel,
        const float* __restrict__ w_root,
        const int* __restrict__ batch,
        ushort* __restrict__ hb,
        float* __restrict__ hsum) {
    __shared__ uint s_wrelp[20 * HID];   // 5 KB: (w[2k][c], w[2k+1][c]) f16x2
    __shared__ uint s_wrootp[20 * HID];  // 5 KB
    __shared__ uint s_a[64][20];         // 5 KB gathered sums (f16x2)
    __shared__ uint s_x[64][20];         // 5 KB own rows (f16x2)
    for (int i = threadIdx.x; i < 20 * HID; i += 256) {
        int kk = i >> 6, cc = i & 63;
        int k0 = 2 * kk, k1 = 2 * kk + 1;
        float r0 = (k0 < F_IN) ? w_rel[k0 * HID + cc] : 0.f;
        float r1 = (k1 < F_IN) ? w_rel[k1 * HID + cc] : 0.f;
        float o0 = (k0 < F_IN) ? w_root[k0 * HID + cc] : 0.f;
        float o1 = (k1 < F_IN) ? w_root[k1 * HID + cc] : 0.f;
        s_wrelp[i]  = (uint)f2h_bits(r0) | ((uint)f2h_bits(r1) << 16);
        s_wrootp[i] = (uint)f2h_bits(o0) | ((uint)f2h_bits(o1) << 16);
    }
    const int wave = threadIdx.x >> 6, lane = threadIdx.x & 63;
    const int half = lane >> 5, l32 = lane & 31;
    const int base = blockIdx.x * 64;

    // Phase A: 2 nodes per iteration, 32 row-loads in flight per wave
    for (int i = 0; i < 8; ++i) {
        int nl = wave * 16 + 2 * i + half;
        int n = base + nl;
        uint xv = 0;
        int dp = 0;
        if (n < N_NODES) {
            int deg = cnt[n]; if (deg > CAPD) deg = CAPD;
            dp = (deg + 15) & ~15; if (dp > CAPD) dp = CAPD;
            if (l32 < 20) xv = xb32[n * 20 + l32];
        }
        h2 sum = {(_Float16)0, (_Float16)0};
        const int* sl = slots + n * CAPD;
        for (int j = 0; j < dp; j += 16) {
            int4 a4 = *(const int4*)(sl + j);
            int4 b4 = *(const int4*)(sl + j + 4);
            int4 c4 = *(const int4*)(sl + j + 8);
            int4 d4 = *(const int4*)(sl + j + 12);
            if (l32 < 20) {
                uint v0 = xb32[clampi(a4.x) * 20 + l32];
                uint v1 = xb32[clampi(a4.y) * 20 + l32];
                uint v2 = xb32[clampi(a4.z) * 20 + l32];
                uint v3 = xb32[clampi(a4.w) * 20 + l32];
                uint v4 = xb32[clampi(b4.x) * 20 + l32];
                uint v5 = xb32[clampi(b4.y) * 20 + l32];
                uint v6 = xb32[clampi(b4.z) * 20 + l32];
                uint v7 = xb32[clampi(b4.w) * 20 + l32];
                uint v8 = xb32[clampi(c4.x) * 20 + l32];
                uint v9 = xb32[clampi(c4.y) * 20 + l32];
                uint va = xb32[clampi(c4.z) * 20 + l32];
                uint vb = xb32[clampi(c4.w) * 20 + l32];
                uint vc = xb32[clampi(d4.x) * 20 + l32];
                uint vd = xb32[clampi(d4.y) * 20 + l32];
                uint ve = xb32[clampi(d4.z) * 20 + l32];
                uint vf = xb32[clampi(d4.w) * 20 + l32];
                h2 t0 = (u2h(v0) + u2h(v1)) + (u2h(v2) + u2h(v3));
                h2 t1 = (u2h(v4) + u2h(v5)) + (u2h(v6) + u2h(v7));
                h2 t2 = (u2h(v8) + u2h(v9)) + (u2h(va) + u2h(vb));
                h2 t3 = (u2h(vc) + u2h(vd)) + (u2h(ve) + u2h(vf));
                sum += (t0 + t1) + (t2 + t3);
            }
        }
        if (l32 < 20) {
            s_a[nl][l32] = h2u(sum);
            s_x[nl][l32] = xv;
        }
    }
    __syncthreads();

    // Phase B: pk_fma against pair-packed weights; single h2 accumulator
    const int c = lane, r = wave;
    const float bias = b_rel[c];
    float psum = 0.f;
    int cur_g = -1;
    for (int i = 0; i < 16; ++i) {
        int nl = r * 16 + i;
        int n = base + nl;
        if (n >= N_NODES) break;
        h2 acc = {(_Float16)0, (_Float16)0};
        #pragma unroll
        for (int k8 = 0; k8 < 5; ++k8) {   // 4 pairs = 8 features per iter
            uint4 pa = *(const uint4*)&s_a[nl][k8 * 4];
            uint4 px = *(const uint4*)&s_x[nl][k8 * 4];
            acc += u2h(pa.x) * u2h(s_wrelp[(k8 * 4 + 0) * HID + c]);
            acc += u2h(pa.y) * u2h(s_wrelp[(k8 * 4 + 1) * HID + c]);
            acc += u2h(pa.z) * u2h(s_wrelp[(k8 * 4 + 2) * HID + c]);
            acc += u2h(pa.w) * u2h(s_wrelp[(k8 * 4 + 3) * HID + c]);
            acc += u2h(px.x) * u2h(s_wrootp[(k8 * 4 + 0) * HID + c]);
            acc += u2h(px.y) * u2h(s_wrootp[(k8 * 4 + 1) * HID + c]);
            acc += u2h(px.z) * u2h(s_wrootp[(k8 * 4 + 2) * HID + c]);
            acc += u2h(px.w) * u2h(s_wrootp[(k8 * 4 + 3) * HID + c]);
        }
        float hv = fmaxf((float)acc.x + (float)acc.y + bias, 0.f);
        hb[(n << 6) + c] = f2h_bits(hv);
        int g = batch[n];
        if (g != cur_g) {
            if (cur_g >= 0) atomicAdd(&hsum[(cur_g << 6) + c], psum);
            psum = 0.f;
            cur_g = g;
        }
        psum += hv;
    }
    if (cur_g >= 0) atomicAdd(&hsum[(cur_g << 6) + c], psum);
}

// ---------------------------------------------------------------------------
// Scatter pass 2 (runs AFTER layer1; ebuf2 aliases the dead slots region):
// bucket edges by src>>8 with payload (src << 8) | batch[dst]  (g < 256).
// This src-grouping is what makes the layer-2 h-gather L2-local.
// ---------------------------------------------------------------------------
__global__ void scatter2_kernel(const int* __restrict__ src,
                                const int* __restrict__ dst,
                                const int* __restrict__ batch,
                                int* __restrict__ gcur2,
                                uint* __restrict__ ebuf2) {
    __shared__ int hist[NB];
    __shared__ int cur[NB];
    for (int i = threadIdx.x; i < NB; i += 256) hist[i] = 0;
    __syncthreads();
    const int base = blockIdx.x * EPB;
    int sv[EPB / 256];
    uint pl[EPB / 256];
    #pragma unroll
    for (int i = 0; i < EPB / 256; ++i) {
        int e = base + i * 256 + threadIdx.x;
        sv[i] = -1;
        if (e < N_EDGES) {
            int s = src[e];
            int g = batch[dst[e]];          // 4-B gather in a 400 KB L2-hot table
            sv[i] = s;
            pl[i] = ((uint)s << 8) | (uint)g;
            atomicAdd(&hist[s >> 8], 1);
        }
    }
    __syncthreads();
    for (int i = threadIdx.x; i < NB; i += 256) {
        int c = hist[i];
        cur[i] = (c > 0) ? atomicAdd(&gcur2[i], c) : 0;
    }
    __syncthreads();
    #pragma unroll
    for (int i = 0; i < EPB / 256; ++i) {
        if (sv[i] >= 0) {
            int b = sv[i] >> 8;
            int pos = atomicAdd(&cur[b], 1);
            if (pos < BCAP) ebuf2[b * BCAP + pos] = pl[i];
        }
    }
}

// ---------------------------------------------------------------------------
// Layer 2 via linearity: esum[g] = sum_e h[src[e]] * [batch[dst[e]]=g].
// One block per src-bucket pair (p, p+196): each bucket's h-rows form a
// 32 KB L2-resident window (256 nodes * 128 B), read per edge; accumulate
// into a 64 KB LDS f32 esum. Channel layout is DE-INTERLEAVED (hv.x -> slot
// l32, hv.y -> slot 32+l32) so both atomics hit all 32 banks 2-way (free).
// Each block writes a 64 KB partial; finalize reduces the 196 partials.
// Replaces the old 205 MB random hb gather entirely.
// ---------------------------------------------------------------------------
__global__ __launch_bounds__(1024) void layer2_kernel(
        const uint* __restrict__ hb32,
        const uint* __restrict__ ebuf2,
        const int* __restrict__ gcur2,
        float* __restrict__ partial) {
    __shared__ float s_es[N_GRAPHS * HID];   // 64 KB, permuted channel layout
    for (int i = threadIdx.x; i < N_GRAPHS * HID; i += 1024) s_es[i] = 0.f;
    __syncthreads();
    const int wave = threadIdx.x >> 6, lane = threadIdx.x & 63;
    const int half = lane >> 5, l32 = lane & 31;
    for (int b = blockIdx.x; b < NB; b += P2) {
        int e1 = gcur2[b]; if (e1 > BCAP) e1 = BCAP;
        const uint* eb = ebuf2 + b * BCAP;
        // 16 waves stride over 64-edge groups; each half-wave handles one edge
        for (int base = wave << 6; base < e1; base += 16 << 6) {
            int cnt = e1 - base; if (cnt > 64) cnt = 64;
            uint pv = (lane < cnt) ? eb[base + lane] : 0u;
            #pragma unroll 4
            for (int k = 0; k < 32; ++k) {
                int idx2 = 2 * k + half;
                uint p = __shfl(pv, idx2, 64);
                if (idx2 < cnt) {
                    int srcn = (int)(p >> 8);
                    int g = (int)(p & 255u);
                    h2 hv = u2h(hb32[(srcn << 5) + l32]);
                    atomicAdd(&s_es[(g << 6) + l32],      (float)hv.x);
                    atomicAdd(&s_es[(g << 6) + 32 + l32], (float)hv.y);
                }
            }
        }
    }
    __syncthreads();
    float* pp = partial + blockIdx.x * (N_GRAPHS * HID);
    for (int i = threadIdx.x; i < N_GRAPHS * HID; i += 1024) pp[i] = s_es[i];
}

// ---------------------------------------------------------------------------
// out[g][c] = relu( (esum[g]@w2_rel + hsum[g]@w2_root + cnt*b2) / max(cnt,1) )
// esum[g][c] reduced from the 196 permuted partials (even c -> c/2, odd ->
// 32 + c/2 within the graph's 64-slot span).
// ---------------------------------------------------------------------------
__global__ void finalize_kernel(const float* __restrict__ partial,
                                const float* __restrict__ hsum,
                                const float* __restrict__ w2_rel,
                                const float* __restrict__ w2_root,
                                const float* __restrict__ b2,
                                const int* __restrict__ batch,
                                float* __restrict__ out) {
    __shared__ float s_e[HID];
    __shared__ float s_h[HID];
    const int g = blockIdx.x;
    const int c = threadIdx.x;
    int idx = (g << 6) + ((c & 1) ? 32 + (c >> 1) : (c >> 1));
    float se = 0.f;
    #pragma unroll 4
    for (int p = 0; p < P2; ++p) se += partial[p * (N_GRAPHS * HID) + idx];
    s_e[c] = se;
    s_h[c] = hsum[(g << 6) + c];
    __syncthreads();

    int lo = 0, hi = N_NODES;
    while (lo < hi) { int m = (lo + hi) >> 1; if (batch[m] < g) lo = m + 1; else hi = m; }
    int start = lo;
    hi = N_NODES;
    while (lo < hi) { int m = (lo + hi) >> 1; if (batch[m] < g + 1) lo = m + 1; else hi = m; }
    int cntg = lo - start;

    float acc = (float)cntg * b2[c];
    #pragma unroll
    for (int k = 0; k < HID; ++k) {
        acc += s_e[k] * w2_rel[k * HID + c];
        acc += s_h[k] * w2_root[k * HID + c];
    }
    float denom = cntg > 0 ? (float)cntg : 1.f;
    out[(g << 6) + c] = fmaxf(acc / denom, 0.f);
}

// ---------------------------------------------------------------------------
extern "C" void kernel_launch(void* const* d_in, const int* in_sizes, int n_in,
                              void* d_out, int out_size, void* d_ws, size_t ws_size,
                              hipStream_t stream) {
    const float* x       = (const float*)d_in[0];
    const int*   ei      = (const int*)  d_in[1];
    const int*   batch   = (const int*)  d_in[2];
    const float* w1_rel  = (const float*)d_in[3];
    const float* b1_rel  = (const float*)d_in[4];
    const float* w1_root = (const float*)d_in[5];
    const float* w2_rel  = (const float*)d_in[6];
    const float* b2_rel  = (const float*)d_in[7];
    const float* w2_root = (const float*)d_in[8];
    float* out = (float*)d_out;

    const int* src = ei;
    const int* dst = ei + N_EDGES;

    // ws layout (bytes), peak ~40.5 MB (unchanged footprint):
    //   [0,       400000)   cnt     N int        (build)
    //   [400000,  465536)   hsum    256*64 f32   (zeroed)
    //   [465536,  467100)   gcur2   NB int       (zeroed; inside old esum slot)
    //   [531072,  532636)   gcur    NB int       (zeroed)
    //   [532640, 19732640)  slots   N*48 int     (tails dummy-filled by build)
    //   [532640,  7739552)  ebuf2   391*4608 uint  } alias slots  (post-layer1)
    //   [7739552, 20584608) partial 196*16384 f32  } alias slots+xb (post-layer1)
    //   [19732640,27732720) xb      (N+1)*40 f16
    //   [19732640,26939552) ebuf    391*4608 uint   (alias xb; dead before pack)
    //   [27732720,40532848) hb      (N+1)*64 f16
    char* wsb = (char*)d_ws;
    int*    cnt     = (int*)   (wsb);
    float*  hsum    = (float*) (wsb + 400000);
    int*    gcur2   = (int*)   (wsb + 465536);
    int*    gcur    = (int*)   (wsb + 531072);
    int*    slots   = (int*)   (wsb + 532640);
    uint*   ebuf2   = (uint*)  (wsb + 532640);
    float*  partial = (float*) (wsb + 7739552);
    ushort* xb      = (ushort*)(wsb + 19732640);
    uint*   ebuf    = (uint*)  (wsb + 19732640);
    ushort* hb      = (ushort*)(wsb + 27732720);

    hipMemsetAsync(wsb + 400000, 0, 132636, stream);  // hsum + gcur2 + gcur

    scatter_kernel<<<NBLK, 256, 0, stream>>>(src, dst, gcur, ebuf);
    build_kernel<<<NB, 256, 0, stream>>>(ebuf, gcur, cnt, slots);

    {   // pack x -> f16 [N+1][40]; zero hb dummy row (after ebuf is dead)
        int total = (N_NODES + 1) * F_PAD;
        pack_x_kernel<<<(total + 255) / 256, 256, 0, stream>>>(x, xb, hb);
    }
    {   // layer 1
        int blocks = (N_NODES + 63) / 64;
        layer1_kernel<<<blocks, 256, 0, stream>>>((const uint*)xb, cnt, slots,
                                                  w1_rel, b1_rel, w1_root, batch,
                                                  hb, hsum);
    }
    // layer 2 (linearity form): src-bucket edges with graph labels, then
    // accumulate h[src] into per-graph LDS sums. slots/xb are dead now.
    scatter2_kernel<<<NBLK, 256, 0, stream>>>(src, dst, batch, gcur2, ebuf2);
    layer2_kernel<<<P2, 1024, 0, stream>>>((const uint*)hb, ebuf2, gcur2, partial);

    finalize_kernel<<<N_GRAPHS, HID, 0, stream>>>(partial, hsum, w2_rel, w2_root,
                                                  b2_rel, batch, out);
}

// Round 2
// 256.903 us; speedup vs baseline: 3.6061x; 3.6061x over previous
//
#include <hip/hip_runtime.h>

#define N_NODES 100000
#define N_EDGES 1600000
#define N_GRAPHS 256
#define F_IN 38
#define F_PAD 40    // x packed to 40 f16 (80 B rows = 20 uints)
#define HID 64
#define CAPD 48     // dst-CSR capacity (in-deg Poisson(16); 48 proven)

// edge partition parameters
#define NB   391    // dst buckets of 256 nodes: bucket = dst >> 8
#define EPB  4096   // edges per chunk-block
#define NBLK 391    // ceil(N_EDGES / EPB)
#define BCAP 4608   // per-bucket ebuf capacity (mean 4096, +8 sigma)

typedef unsigned short ushort;
typedef unsigned int uint;
typedef _Float16 h2 __attribute__((ext_vector_type(2)));

__device__ __forceinline__ h2 u2h(uint u) {
    union { uint u; h2 h; } v; v.u = u; return v.h;
}
__device__ __forceinline__ uint h2u(h2 h) {
    union { uint u; h2 h; } v; v.h = h; return v.u;
}
__device__ __forceinline__ ushort f2h_bits(float f) {
    union { _Float16 h; ushort s; } v; v.h = (_Float16)f; return v.s;
}
// Defensive clamp: any out-of-range index maps to the all-zero dummy row N_NODES.
__device__ __forceinline__ int clampi(int v) {
    return (int)min((uint)v, (uint)N_NODES);
}

// ---------------------------------------------------------------------------
// Pack x [N][38] fp32 -> xb [N+1][40] f16 (zero cols 38..39; row N all-zero).
// Also zeroes the hb dummy row N.
// ---------------------------------------------------------------------------
__global__ void pack_x_kernel(const float* __restrict__ x,
                              ushort* __restrict__ xb,
                              ushort* __restrict__ hb) {
    int tid = blockIdx.x * blockDim.x + threadIdx.x;
    if (tid < HID) hb[(N_NODES << 6) + tid] = 0;
    if (tid >= (N_NODES + 1) * F_PAD) return;
    int n = tid / F_PAD;
    int f = tid - n * F_PAD;
    float v = (n < N_NODES && f < F_IN) ? x[n * F_IN + f] : 0.0f;
    xb[tid] = f2h_bits(v);
}

// ---------------------------------------------------------------------------
// Scatter edges into fixed-capacity dst-bucket regions of ebuf.
// Payload compressed to one uint: (src << 8) | (dst & 255)  (src < 2^17).
// ---------------------------------------------------------------------------
__global__ void scatter_kernel(const int* __restrict__ src,
                               const int* __restrict__ dst,
                               int* __restrict__ gcur,
                               uint* __restrict__ ebuf) {
    __shared__ int hist[NB];
    __shared__ int cur[NB];
    for (int i = threadIdx.x; i < NB; i += 256) hist[i] = 0;
    __syncthreads();
    const int base = blockIdx.x * EPB;
    int d[EPB / 256];
    uint pl[EPB / 256];
    #pragma unroll
    for (int i = 0; i < EPB / 256; ++i) {
        int e = base + i * 256 + threadIdx.x;
        d[i] = (e < N_EDGES) ? dst[e] : -1;
        if (d[i] >= 0) {
            pl[i] = ((uint)src[e] << 8) | ((uint)d[i] & 255u);
            atomicAdd(&hist[d[i] >> 8], 1);
        }
    }
    __syncthreads();
    for (int i = threadIdx.x; i < NB; i += 256) {
        int c = hist[i];
        cur[i] = (c > 0) ? atomicAdd(&gcur[i], c) : 0;
    }
    __syncthreads();
    #pragma unroll
    for (int i = 0; i < EPB / 256; ++i) {
        if (d[i] >= 0) {
            int b = d[i] >> 8;
            int pos = atomicAdd(&cur[b], 1);
            if (pos < BCAP) ebuf[b * BCAP + pos] = pl[i];
        }
    }
}

// ---------------------------------------------------------------------------
// One block per dst-bucket builds its 256 nodes' slot lists.
// Explicitly fills the rounded-up tail [deg, dp) with the dummy row index
// N_NODES, so slot tails never depend on workspace poison.
// ---------------------------------------------------------------------------
__global__ void build_kernel(const uint* __restrict__ ebuf,
                             const int* __restrict__ gcur,
                             int* __restrict__ cnt,
                             int* __restrict__ slots) {
    __shared__ int cl[256];
    const int b = blockIdx.x;
    cl[threadIdx.x] = 0;
    __syncthreads();
    int e1 = gcur[b]; if (e1 > BCAP) e1 = BCAP;
    for (int idx = threadIdx.x; idx < e1; idx += 256) {
        uint e = ebuf[b * BCAP + idx];
        int dl = (int)(e & 255u);
        int pos = atomicAdd(&cl[dl], 1);
        if (pos < CAPD) slots[((b << 8) + dl) * CAPD + pos] = (int)(e >> 8);
    }
    __syncthreads();
    int n = (b << 8) + threadIdx.x;
    if (n < N_NODES) {
        int c = cl[threadIdx.x];
        cnt[n] = c;
        int d = (c > CAPD) ? CAPD : c;
        int dp = (d + 15) & ~15; if (dp > CAPD) dp = CAPD;
        for (int j = d; j < dp; ++j) slots[n * CAPD + j] = N_NODES;  // dummy row
    }
}

// ---------------------------------------------------------------------------
// Layer 1 fused (proven r17 Phase B, dual-node Phase A). OCCUPANCY BUMP:
// launch_bounds (256,8) -> 8 blocks/CU (LDS 20KB*8 = 160KB exactly, VGPR 28
// fits the 64-cap). Doubles resident waves 16->32/CU to hide gather latency
// (r0 counters: Occ 49.5%, VALUBusy 32%, HBM 21% => latency-bound).
// ---------------------------------------------------------------------------
__global__ __launch_bounds__(256, 8) void layer1_kernel(
        const uint* __restrict__ xb32,
        const int* __restrict__ cnt,
        const int* __restrict__ slots,
        const float* __restrict__ w_rel,
        const float* __restrict__ b_rel,
        const float* __restrict__ w_root,
        const int* __restrict__ batch,
        ushort* __restrict__ hb,
        float* __restrict__ hsum) {
    __shared__ uint s_wrelp[20 * HID];   // 5 KB: (w[2k][c], w[2k+1][c]) f16x2
    __shared__ uint s_wrootp[20 * HID];  // 5 KB
    __shared__ uint s_a[64][20];         // 5 KB gathered sums (f16x2)
    __shared__ uint s_x[64][20];         // 5 KB own rows (f16x2)
    for (int i = threadIdx.x; i < 20 * HID; i += 256) {
        int kk = i >> 6, cc = i & 63;
        int k0 = 2 * kk, k1 = 2 * kk + 1;
        float r0 = (k0 < F_IN) ? w_rel[k0 * HID + cc] : 0.f;
        float r1 = (k1 < F_IN) ? w_rel[k1 * HID + cc] : 0.f;
        float o0 = (k0 < F_IN) ? w_root[k0 * HID + cc] : 0.f;
        float o1 = (k1 < F_IN) ? w_root[k1 * HID + cc] : 0.f;
        s_wrelp[i]  = (uint)f2h_bits(r0) | ((uint)f2h_bits(r1) << 16);
        s_wrootp[i] = (uint)f2h_bits(o0) | ((uint)f2h_bits(o1) << 16);
    }
    const int wave = threadIdx.x >> 6, lane = threadIdx.x & 63;
    const int half = lane >> 5, l32 = lane & 31;
    const int base = blockIdx.x * 64;

    // Phase A: 2 nodes per iteration, 32 row-loads in flight per wave
    for (int i = 0; i < 8; ++i) {
        int nl = wave * 16 + 2 * i + half;
        int n = base + nl;
        uint xv = 0;
        int dp = 0;
        if (n < N_NODES) {
            int deg = cnt[n]; if (deg > CAPD) deg = CAPD;
            dp = (deg + 15) & ~15; if (dp > CAPD) dp = CAPD;
            if (l32 < 20) xv = xb32[n * 20 + l32];
        }
        h2 sum = {(_Float16)0, (_Float16)0};
        const int* sl = slots + n * CAPD;
        for (int j = 0; j < dp; j += 16) {
            int4 a4 = *(const int4*)(sl + j);
            int4 b4 = *(const int4*)(sl + j + 4);
            int4 c4 = *(const int4*)(sl + j + 8);
            int4 d4 = *(const int4*)(sl + j + 12);
            if (l32 < 20) {
                uint v0 = xb32[clampi(a4.x) * 20 + l32];
                uint v1 = xb32[clampi(a4.y) * 20 + l32];
                uint v2 = xb32[clampi(a4.z) * 20 + l32];
                uint v3 = xb32[clampi(a4.w) * 20 + l32];
                uint v4 = xb32[clampi(b4.x) * 20 + l32];
                uint v5 = xb32[clampi(b4.y) * 20 + l32];
                uint v6 = xb32[clampi(b4.z) * 20 + l32];
                uint v7 = xb32[clampi(b4.w) * 20 + l32];
                uint v8 = xb32[clampi(c4.x) * 20 + l32];
                uint v9 = xb32[clampi(c4.y) * 20 + l32];
                uint va = xb32[clampi(c4.z) * 20 + l32];
                uint vb = xb32[clampi(c4.w) * 20 + l32];
                uint vc = xb32[clampi(d4.x) * 20 + l32];
                uint vd = xb32[clampi(d4.y) * 20 + l32];
                uint ve = xb32[clampi(d4.z) * 20 + l32];
                uint vf = xb32[clampi(d4.w) * 20 + l32];
                h2 t0 = (u2h(v0) + u2h(v1)) + (u2h(v2) + u2h(v3));
                h2 t1 = (u2h(v4) + u2h(v5)) + (u2h(v6) + u2h(v7));
                h2 t2 = (u2h(v8) + u2h(v9)) + (u2h(va) + u2h(vb));
                h2 t3 = (u2h(vc) + u2h(vd)) + (u2h(ve) + u2h(vf));
                sum += (t0 + t1) + (t2 + t3);
            }
        }
        if (l32 < 20) {
            s_a[nl][l32] = h2u(sum);
            s_x[nl][l32] = xv;
        }
    }
    __syncthreads();

    // Phase B: pk_fma against pair-packed weights; single h2 accumulator
    const int c = lane, r = wave;
    const float bias = b_rel[c];
    float psum = 0.f;
    int cur_g = -1;
    for (int i = 0; i < 16; ++i) {
        int nl = r * 16 + i;
        int n = base + nl;
        if (n >= N_NODES) break;
        h2 acc = {(_Float16)0, (_Float16)0};
        #pragma unroll
        for (int k8 = 0; k8 < 5; ++k8) {   // 4 pairs = 8 features per iter
            uint4 pa = *(const uint4*)&s_a[nl][k8 * 4];
            uint4 px = *(const uint4*)&s_x[nl][k8 * 4];
            acc += u2h(pa.x) * u2h(s_wrelp[(k8 * 4 + 0) * HID + c]);
            acc += u2h(pa.y) * u2h(s_wrelp[(k8 * 4 + 1) * HID + c]);
            acc += u2h(pa.z) * u2h(s_wrelp[(k8 * 4 + 2) * HID + c]);
            acc += u2h(pa.w) * u2h(s_wrelp[(k8 * 4 + 3) * HID + c]);
            acc += u2h(px.x) * u2h(s_wrootp[(k8 * 4 + 0) * HID + c]);
            acc += u2h(px.y) * u2h(s_wrootp[(k8 * 4 + 1) * HID + c]);
            acc += u2h(px.z) * u2h(s_wrootp[(k8 * 4 + 2) * HID + c]);
            acc += u2h(px.w) * u2h(s_wrootp[(k8 * 4 + 3) * HID + c]);
        }
        float hv = fmaxf((float)acc.x + (float)acc.y + bias, 0.f);
        hb[(n << 6) + c] = f2h_bits(hv);
        int g = batch[n];
        if (g != cur_g) {
            if (cur_g >= 0) atomicAdd(&hsum[(cur_g << 6) + c], psum);
            psum = 0.f;
            cur_g = g;
        }
        psum += hv;
    }
    if (cur_g >= 0) atomicAdd(&hsum[(cur_g << 6) + c], psum);
}

// ---------------------------------------------------------------------------
// Layer 2 (PROVEN r0 structure): dual-node f16x2 gather + pool — lanes 0-31 =
// even node's channel pairs, lanes 32-63 = odd node's. Per-graph sums go to
// global f32 atomics once per (lane, graph-run). OCCUPANCY BUMP: (256,8) —
// zero LDS, low VGPR; doubles resident waves for the 205 MB random hb gather.
// (r1's per-edge LDS-atomic rewrite was 10x slower — LDS atomics serialize;
// do not revisit without register accumulation.)
// ---------------------------------------------------------------------------
__global__ __launch_bounds__(256, 8) void layer2_kernel(
        const uint* __restrict__ hb32,
        const int* __restrict__ cnt,
        const int* __restrict__ slots,
        const int* __restrict__ batch,
        float* __restrict__ esum) {
    const int wave = threadIdx.x >> 6, lane = threadIdx.x & 63;
    const int half = lane >> 5, l32 = lane & 31;
    const int base = blockIdx.x * 64;

    float psum0 = 0.f, psum1 = 0.f;
    int cur_g = -1;
    for (int i = 0; i < 8; ++i) {
        int n = base + wave * 16 + 2 * i + half;
        if (n < N_NODES) {
            int deg = cnt[n]; if (deg > CAPD) deg = CAPD;
            int dp = (deg + 15) & ~15; if (dp > CAPD) dp = CAPD;
            h2 sum = {(_Float16)0, (_Float16)0};
            const int* sl = slots + n * CAPD;
            for (int j = 0; j < dp; j += 16) {
                int4 a4 = *(const int4*)(sl + j);
                int4 b4 = *(const int4*)(sl + j + 4);
                int4 c4 = *(const int4*)(sl + j + 8);
                int4 d4 = *(const int4*)(sl + j + 12);
                uint v0 = hb32[(clampi(a4.x) << 5) + l32];
                uint v1 = hb32[(clampi(a4.y) << 5) + l32];
                uint v2 = hb32[(clampi(a4.z) << 5) + l32];
                uint v3 = hb32[(clampi(a4.w) << 5) + l32];
                uint v4 = hb32[(clampi(b4.x) << 5) + l32];
                uint v5 = hb32[(clampi(b4.y) << 5) + l32];
                uint v6 = hb32[(clampi(b4.z) << 5) + l32];
                uint v7 = hb32[(clampi(b4.w) << 5) + l32];
                uint v8 = hb32[(clampi(c4.x) << 5) + l32];
                uint v9 = hb32[(clampi(c4.y) << 5) + l32];
                uint va = hb32[(clampi(c4.z) << 5) + l32];
                uint vb = hb32[(clampi(c4.w) << 5) + l32];
                uint vc = hb32[(clampi(d4.x) << 5) + l32];
                uint vd = hb32[(clampi(d4.y) << 5) + l32];
                uint ve = hb32[(clampi(d4.z) << 5) + l32];
                uint vf = hb32[(clampi(d4.w) << 5) + l32];
                h2 t0 = (u2h(v0) + u2h(v1)) + (u2h(v2) + u2h(v3));
                h2 t1 = (u2h(v4) + u2h(v5)) + (u2h(v6) + u2h(v7));
                h2 t2 = (u2h(v8) + u2h(v9)) + (u2h(va) + u2h(vb));
                h2 t3 = (u2h(vc) + u2h(vd)) + (u2h(ve) + u2h(vf));
                sum += (t0 + t1) + (t2 + t3);
            }
            int g = batch[n];
            if (g != cur_g) {
                if (cur_g >= 0) {
                    atomicAdd(&esum[(cur_g << 6) + 2 * l32], psum0);
                    atomicAdd(&esum[(cur_g << 6) + 2 * l32 + 1], psum1);
                }
                psum0 = 0.f; psum1 = 0.f;
                cur_g = g;
            }
            psum0 += (float)sum.x;
            psum1 += (float)sum.y;
        }
    }
    if (cur_g >= 0) {
        atomicAdd(&esum[(cur_g << 6) + 2 * l32], psum0);
        atomicAdd(&esum[(cur_g << 6) + 2 * l32 + 1], psum1);
    }
}

// ---------------------------------------------------------------------------
// out[g][c] = relu( (esum[g]@w2_rel + hsum[g]@w2_root + cnt*b2) / max(cnt,1) )
// ---------------------------------------------------------------------------
__global__ void finalize_kernel(const float* __restrict__ esum,
                                const float* __restrict__ hsum,
                                const float* __restrict__ w2_rel,
                                const float* __restrict__ w2_root,
                                const float* __restrict__ b2,
                                const int* __restrict__ batch,
                                float* __restrict__ out) {
    __shared__ float s_e[HID];
    __shared__ float s_h[HID];
    const int g = blockIdx.x;
    const int c = threadIdx.x;
    s_e[c] = esum[(g << 6) + c];
    s_h[c] = hsum[(g << 6) + c];
    __syncthreads();

    int lo = 0, hi = N_NODES;
    while (lo < hi) { int m = (lo + hi) >> 1; if (batch[m] < g) lo = m + 1; else hi = m; }
    int start = lo;
    hi = N_NODES;
    while (lo < hi) { int m = (lo + hi) >> 1; if (batch[m] < g + 1) lo = m + 1; else hi = m; }
    int cntg = lo - start;

    float acc = (float)cntg * b2[c];
    #pragma unroll
    for (int k = 0; k < HID; ++k) {
        acc += s_e[k] * w2_rel[k * HID + c];
        acc += s_h[k] * w2_root[k * HID + c];
    }
    float denom = cntg > 0 ? (float)cntg : 1.f;
    out[(g << 6) + c] = fmaxf(acc / denom, 0.f);
}

// ---------------------------------------------------------------------------
extern "C" void kernel_launch(void* const* d_in, const int* in_sizes, int n_in,
                              void* d_out, int out_size, void* d_ws, size_t ws_size,
                              hipStream_t stream) {
    const float* x       = (const float*)d_in[0];
    const int*   ei      = (const int*)  d_in[1];
    const int*   batch   = (const int*)  d_in[2];
    const float* w1_rel  = (const float*)d_in[3];
    const float* b1_rel  = (const float*)d_in[4];
    const float* w1_root = (const float*)d_in[5];
    const float* w2_rel  = (const float*)d_in[6];
    const float* b2_rel  = (const float*)d_in[7];
    const float* w2_root = (const float*)d_in[8];
    float* out = (float*)d_out;

    const int* src = ei;
    const int* dst = ei + N_EDGES;

    // ws layout (bytes), peak ~40.5 MB:
    //   [0,       400000)   cnt    N int   (written by build_kernel)
    //   [400000,  465536)   hsum   256*64 f32 (zeroed)
    //   [465536,  531072)   esum   256*64 f32 (zeroed)
    //   [531072,  532636)   gcur   NB int  (zeroed)
    //   [532640, 19732640)  slots  N*48 int (tails dummy-filled by build)
    //   [19732640,27732720) xb     (N+1)*40 f16  } ebuf (391*4608 uint)
    //   [27732720,40532848) hb     (N+1)*64 f16  } aliases xb; ebuf dead
    //   [19732640,26939552) ebuf (alias)           before pack_x runs
    char* wsb = (char*)d_ws;
    int*    cnt   = (int*)   (wsb);
    float*  hsum  = (float*) (wsb + 400000);
    float*  esum  = (float*) (wsb + 465536);
    int*    gcur  = (int*)   (wsb + 531072);
    int*    slots = (int*)   (wsb + 532640);
    ushort* xb    = (ushort*)(wsb + 19732640);
    ushort* hb    = (ushort*)(wsb + 27732720);
    uint*   ebuf  = (uint*)  (wsb + 19732640);   // alias, see above

    hipMemsetAsync(wsb + 400000, 0, 132636, stream);  // hsum + esum + gcur

    scatter_kernel<<<NBLK, 256, 0, stream>>>(src, dst, gcur, ebuf);
    build_kernel<<<NB, 256, 0, stream>>>(ebuf, gcur, cnt, slots);

    {   // pack x -> f16 [N+1][40]; zero hb dummy row (after ebuf is dead)
        int total = (N_NODES + 1) * F_PAD;
        pack_x_kernel<<<(total + 255) / 256, 256, 0, stream>>>(x, xb, hb);
    }
    {   // layer 1
        int blocks = (N_NODES + 63) / 64;
        layer1_kernel<<<blocks, 256, 0, stream>>>((const uint*)xb, cnt, slots,
                                                  w1_rel, b1_rel, w1_root, batch,
                                                  hb, hsum);
    }
    {   // layer 2: gather + per-graph pooling only
        int blocks = (N_NODES + 63) / 64;
        layer2_kernel<<<blocks, 256, 0, stream>>>((const uint*)hb, cnt, slots,
                                                  batch, esum);
    }
    {   // finalize: esum@w2_rel + hsum@w2_root + bias, mean, relu
        finalize_kernel<<<N_GRAPHS, HID, 0, stream>>>(esum, hsum, w2_rel, w2_root,
                                                      b2_rel, batch, out);
    }
}

// Round 3
// 250.292 us; speedup vs baseline: 3.7013x; 1.0264x over previous
//
#include <hip/hip_runtime.h>

#define N_NODES 100000
#define N_EDGES 1600000
#define N_GRAPHS 256
#define F_IN 38
#define F_PAD 40    // x packed to 40 f16 (80 B rows = 20 uints)
#define HID 64
#define CAPD 48     // dst-CSR capacity (in-deg Poisson(16); 48 proven)

// edge partition parameters
#define NB   391    // dst buckets of 256 nodes: bucket = dst >> 8
#define EPB  4096   // edges per chunk-block
#define NBLK 391    // ceil(N_EDGES / EPB)
#define BCAP 4608   // per-bucket ebuf capacity (mean 4096, +8 sigma)

typedef unsigned short ushort;
typedef unsigned int uint;
typedef _Float16 h2 __attribute__((ext_vector_type(2)));

__device__ __forceinline__ h2 u2h(uint u) {
    union { uint u; h2 h; } v; v.u = u; return v.h;
}
__device__ __forceinline__ uint h2u(h2 h) {
    union { uint u; h2 h; } v; v.h = h; return v.u;
}
__device__ __forceinline__ ushort f2h_bits(float f) {
    union { _Float16 h; ushort s; } v; v.h = (_Float16)f; return v.s;
}
// Defensive clamp: any out-of-range index maps to the all-zero dummy row N_NODES.
__device__ __forceinline__ int clampi(int v) {
    return (int)min((uint)v, (uint)N_NODES);
}

// ---------------------------------------------------------------------------
// Pack x [N][38] fp32 -> xb [N+1][40] f16 (zero cols 38..39; row N all-zero).
// Also zeroes the hb dummy row N.
// ---------------------------------------------------------------------------
__global__ void pack_x_kernel(const float* __restrict__ x,
                              ushort* __restrict__ xb,
                              ushort* __restrict__ hb) {
    int tid = blockIdx.x * blockDim.x + threadIdx.x;
    if (tid < HID) hb[(N_NODES << 6) + tid] = 0;
    if (tid >= (N_NODES + 1) * F_PAD) return;
    int n = tid / F_PAD;
    int f = tid - n * F_PAD;
    float v = (n < N_NODES && f < F_IN) ? x[n * F_IN + f] : 0.0f;
    xb[tid] = f2h_bits(v);
}

// ---------------------------------------------------------------------------
// Scatter edges into fixed-capacity dst-bucket regions of ebuf.
// Payload compressed to one uint: (src << 8) | (dst & 255)  (src < 2^17).
// ---------------------------------------------------------------------------
__global__ void scatter_kernel(const int* __restrict__ src,
                               const int* __restrict__ dst,
                               int* __restrict__ gcur,
                               uint* __restrict__ ebuf) {
    __shared__ int hist[NB];
    __shared__ int cur[NB];
    for (int i = threadIdx.x; i < NB; i += 256) hist[i] = 0;
    __syncthreads();
    const int base = blockIdx.x * EPB;
    int d[EPB / 256];
    uint pl[EPB / 256];
    #pragma unroll
    for (int i = 0; i < EPB / 256; ++i) {
        int e = base + i * 256 + threadIdx.x;
        d[i] = (e < N_EDGES) ? dst[e] : -1;
        if (d[i] >= 0) {
            pl[i] = ((uint)src[e] << 8) | ((uint)d[i] & 255u);
            atomicAdd(&hist[d[i] >> 8], 1);
        }
    }
    __syncthreads();
    for (int i = threadIdx.x; i < NB; i += 256) {
        int c = hist[i];
        cur[i] = (c > 0) ? atomicAdd(&gcur[i], c) : 0;
    }
    __syncthreads();
    #pragma unroll
    for (int i = 0; i < EPB / 256; ++i) {
        if (d[i] >= 0) {
            int b = d[i] >> 8;
            int pos = atomicAdd(&cur[b], 1);
            if (pos < BCAP) ebuf[b * BCAP + pos] = pl[i];
        }
    }
}

// ---------------------------------------------------------------------------
// Build v2 (LDS-staged): one block per dst-bucket. The bucket's whole slot
// table (256 nodes x 48 slots = 48 KB) lives in LDS, pre-filled with the
// dummy row index N_NODES (this also replaces the old per-thread tail-fill
// loop). Edges scatter into LDS (cheap banked writes), then the table is
// dumped to global as coalesced int4 stores. Replaces ~1.6M scattered 4-B
// global stores (~100 MB of line-RMW traffic) with 19.2 MB streaming.
// ---------------------------------------------------------------------------
__global__ __launch_bounds__(256, 3) void build_kernel(
        const uint* __restrict__ ebuf,
        const int* __restrict__ gcur,
        int* __restrict__ cnt,
        int* __restrict__ slots) {
    __shared__ int cl[256];
    __shared__ int s_slots[256 * CAPD];   // 48 KB
    const int b = blockIdx.x;
    cl[threadIdx.x] = 0;
    for (int i = threadIdx.x; i < 256 * CAPD; i += 256) s_slots[i] = N_NODES;
    __syncthreads();
    int e1 = gcur[b]; if (e1 > BCAP) e1 = BCAP;
    for (int idx = threadIdx.x; idx < e1; idx += 256) {
        uint e = ebuf[b * BCAP + idx];
        int dl = (int)(e & 255u);
        int pos = atomicAdd(&cl[dl], 1);
        if (pos < CAPD) s_slots[dl * CAPD + pos] = (int)(e >> 8);
    }
    __syncthreads();
    int n = (b << 8) + threadIdx.x;
    if (n < N_NODES) cnt[n] = cl[threadIdx.x];
    // Coalesced dump; clamp rows to N_NODES so the last bucket never writes
    // past the slots region.
    int nrows = N_NODES - (b << 8);
    if (nrows > 256) nrows = 256;
    int lim = nrows * (CAPD / 4);             // int4 count
    const int4* sp = (const int4*)s_slots;
    int4* gp = (int4*)(slots + b * 256 * CAPD);
    for (int i = threadIdx.x; i < lim; i += 256) gp[i] = sp[i];
}

// ---------------------------------------------------------------------------
// Layer 1 fused (proven r17 Phase B, dual-node Phase A).
// ---------------------------------------------------------------------------
__global__ __launch_bounds__(256, 4) void layer1_kernel(
        const uint* __restrict__ xb32,
        const int* __restrict__ cnt,
        const int* __restrict__ slots,
        const float* __restrict__ w_rel,
        const float* __restrict__ b_rel,
        const float* __restrict__ w_root,
        const int* __restrict__ batch,
        ushort* __restrict__ hb,
        float* __restrict__ hsum) {
    __shared__ uint s_wrelp[20 * HID];   // 5 KB: (w[2k][c], w[2k+1][c]) f16x2
    __shared__ uint s_wrootp[20 * HID];  // 5 KB
    __shared__ uint s_a[64][20];         // 5 KB gathered sums (f16x2)
    __shared__ uint s_x[64][20];         // 5 KB own rows (f16x2)
    for (int i = threadIdx.x; i < 20 * HID; i += 256) {
        int kk = i >> 6, cc = i & 63;
        int k0 = 2 * kk, k1 = 2 * kk + 1;
        float r0 = (k0 < F_IN) ? w_rel[k0 * HID + cc] : 0.f;
        float r1 = (k1 < F_IN) ? w_rel[k1 * HID + cc] : 0.f;
        float o0 = (k0 < F_IN) ? w_root[k0 * HID + cc] : 0.f;
        float o1 = (k1 < F_IN) ? w_root[k1 * HID + cc] : 0.f;
        s_wrelp[i]  = (uint)f2h_bits(r0) | ((uint)f2h_bits(r1) << 16);
        s_wrootp[i] = (uint)f2h_bits(o0) | ((uint)f2h_bits(o1) << 16);
    }
    const int wave = threadIdx.x >> 6, lane = threadIdx.x & 63;
    const int half = lane >> 5, l32 = lane & 31;
    const int base = blockIdx.x * 64;

    // Phase A: 2 nodes per iteration, 32 row-loads in flight per wave
    for (int i = 0; i < 8; ++i) {
        int nl = wave * 16 + 2 * i + half;
        int n = base + nl;
        uint xv = 0;
        int dp = 0;
        if (n < N_NODES) {
            int deg = cnt[n]; if (deg > CAPD) deg = CAPD;
            dp = (deg + 15) & ~15; if (dp > CAPD) dp = CAPD;
            if (l32 < 20) xv = xb32[n * 20 + l32];
        }
        h2 sum = {(_Float16)0, (_Float16)0};
        const int* sl = slots + n * CAPD;
        for (int j = 0; j < dp; j += 16) {
            int4 a4 = *(const int4*)(sl + j);
            int4 b4 = *(const int4*)(sl + j + 4);
            int4 c4 = *(const int4*)(sl + j + 8);
            int4 d4 = *(const int4*)(sl + j + 12);
            if (l32 < 20) {
                uint v0 = xb32[clampi(a4.x) * 20 + l32];
                uint v1 = xb32[clampi(a4.y) * 20 + l32];
                uint v2 = xb32[clampi(a4.z) * 20 + l32];
                uint v3 = xb32[clampi(a4.w) * 20 + l32];
                uint v4 = xb32[clampi(b4.x) * 20 + l32];
                uint v5 = xb32[clampi(b4.y) * 20 + l32];
                uint v6 = xb32[clampi(b4.z) * 20 + l32];
                uint v7 = xb32[clampi(b4.w) * 20 + l32];
                uint v8 = xb32[clampi(c4.x) * 20 + l32];
                uint v9 = xb32[clampi(c4.y) * 20 + l32];
                uint va = xb32[clampi(c4.z) * 20 + l32];
                uint vb = xb32[clampi(c4.w) * 20 + l32];
                uint vc = xb32[clampi(d4.x) * 20 + l32];
                uint vd = xb32[clampi(d4.y) * 20 + l32];
                uint ve = xb32[clampi(d4.z) * 20 + l32];
                uint vf = xb32[clampi(d4.w) * 20 + l32];
                h2 t0 = (u2h(v0) + u2h(v1)) + (u2h(v2) + u2h(v3));
                h2 t1 = (u2h(v4) + u2h(v5)) + (u2h(v6) + u2h(v7));
                h2 t2 = (u2h(v8) + u2h(v9)) + (u2h(va) + u2h(vb));
                h2 t3 = (u2h(vc) + u2h(vd)) + (u2h(ve) + u2h(vf));
                sum += (t0 + t1) + (t2 + t3);
            }
        }
        if (l32 < 20) {
            s_a[nl][l32] = h2u(sum);
            s_x[nl][l32] = xv;
        }
    }
    __syncthreads();

    // Phase B: pk_fma against pair-packed weights; single h2 accumulator
    const int c = lane, r = wave;
    const float bias = b_rel[c];
    float psum = 0.f;
    int cur_g = -1;
    for (int i = 0; i < 16; ++i) {
        int nl = r * 16 + i;
        int n = base + nl;
        if (n >= N_NODES) break;
        h2 acc = {(_Float16)0, (_Float16)0};
        #pragma unroll
        for (int k8 = 0; k8 < 5; ++k8) {   // 4 pairs = 8 features per iter
            uint4 pa = *(const uint4*)&s_a[nl][k8 * 4];
            uint4 px = *(const uint4*)&s_x[nl][k8 * 4];
            acc += u2h(pa.x) * u2h(s_wrelp[(k8 * 4 + 0) * HID + c]);
            acc += u2h(pa.y) * u2h(s_wrelp[(k8 * 4 + 1) * HID + c]);
            acc += u2h(pa.z) * u2h(s_wrelp[(k8 * 4 + 2) * HID + c]);
            acc += u2h(pa.w) * u2h(s_wrelp[(k8 * 4 + 3) * HID + c]);
            acc += u2h(px.x) * u2h(s_wrootp[(k8 * 4 + 0) * HID + c]);
            acc += u2h(px.y) * u2h(s_wrootp[(k8 * 4 + 1) * HID + c]);
            acc += u2h(px.z) * u2h(s_wrootp[(k8 * 4 + 2) * HID + c]);
            acc += u2h(px.w) * u2h(s_wrootp[(k8 * 4 + 3) * HID + c]);
        }
        float hv = fmaxf((float)acc.x + (float)acc.y + bias, 0.f);
        hb[(n << 6) + c] = f2h_bits(hv);
        int g = batch[n];
        if (g != cur_g) {
            if (cur_g >= 0) atomicAdd(&hsum[(cur_g << 6) + c], psum);
            psum = 0.f;
            cur_g = g;
        }
        psum += hv;
    }
    if (cur_g >= 0) atomicAdd(&hsum[(cur_g << 6) + c], psum);
}

// ---------------------------------------------------------------------------
// Layer 2 (proven r0 structure): dual-node f16x2 gather + pool.
// ---------------------------------------------------------------------------
__global__ __launch_bounds__(256, 8) void layer2_kernel(
        const uint* __restrict__ hb32,
        const int* __restrict__ cnt,
        const int* __restrict__ slots,
        const int* __restrict__ batch,
        float* __restrict__ esum) {
    const int wave = threadIdx.x >> 6, lane = threadIdx.x & 63;
    const int half = lane >> 5, l32 = lane & 31;
    const int base = blockIdx.x * 64;

    float psum0 = 0.f, psum1 = 0.f;
    int cur_g = -1;
    for (int i = 0; i < 8; ++i) {
        int n = base + wave * 16 + 2 * i + half;
        if (n < N_NODES) {
            int deg = cnt[n]; if (deg > CAPD) deg = CAPD;
            int dp = (deg + 15) & ~15; if (dp > CAPD) dp = CAPD;
            h2 sum = {(_Float16)0, (_Float16)0};
            const int* sl = slots + n * CAPD;
            for (int j = 0; j < dp; j += 16) {
                int4 a4 = *(const int4*)(sl + j);
                int4 b4 = *(const int4*)(sl + j + 4);
                int4 c4 = *(const int4*)(sl + j + 8);
                int4 d4 = *(const int4*)(sl + j + 12);
                uint v0 = hb32[(clampi(a4.x) << 5) + l32];
                uint v1 = hb32[(clampi(a4.y) << 5) + l32];
                uint v2 = hb32[(clampi(a4.z) << 5) + l32];
                uint v3 = hb32[(clampi(a4.w) << 5) + l32];
                uint v4 = hb32[(clampi(b4.x) << 5) + l32];
                uint v5 = hb32[(clampi(b4.y) << 5) + l32];
                uint v6 = hb32[(clampi(b4.z) << 5) + l32];
                uint v7 = hb32[(clampi(b4.w) << 5) + l32];
                uint v8 = hb32[(clampi(c4.x) << 5) + l32];
                uint v9 = hb32[(clampi(c4.y) << 5) + l32];
                uint va = hb32[(clampi(c4.z) << 5) + l32];
                uint vb = hb32[(clampi(c4.w) << 5) + l32];
                uint vc = hb32[(clampi(d4.x) << 5) + l32];
                uint vd = hb32[(clampi(d4.y) << 5) + l32];
                uint ve = hb32[(clampi(d4.z) << 5) + l32];
                uint vf = hb32[(clampi(d4.w) << 5) + l32];
                h2 t0 = (u2h(v0) + u2h(v1)) + (u2h(v2) + u2h(v3));
                h2 t1 = (u2h(v4) + u2h(v5)) + (u2h(v6) + u2h(v7));
                h2 t2 = (u2h(v8) + u2h(v9)) + (u2h(va) + u2h(vb));
                h2 t3 = (u2h(vc) + u2h(vd)) + (u2h(ve) + u2h(vf));
                sum += (t0 + t1) + (t2 + t3);
            }
            int g = batch[n];
            if (g != cur_g) {
                if (cur_g >= 0) {
                    atomicAdd(&esum[(cur_g << 6) + 2 * l32], psum0);
                    atomicAdd(&esum[(cur_g << 6) + 2 * l32 + 1], psum1);
                }
                psum0 = 0.f; psum1 = 0.f;
                cur_g = g;
            }
            psum0 += (float)sum.x;
            psum1 += (float)sum.y;
        }
    }
    if (cur_g >= 0) {
        atomicAdd(&esum[(cur_g << 6) + 2 * l32], psum0);
        atomicAdd(&esum[(cur_g << 6) + 2 * l32 + 1], psum1);
    }
}

// ---------------------------------------------------------------------------
// out[g][c] = relu( (esum[g]@w2_rel + hsum[g]@w2_root + cnt*b2) / max(cnt,1) )
// ---------------------------------------------------------------------------
__global__ void finalize_kernel(const float* __restrict__ esum,
                                const float* __restrict__ hsum,
                                const float* __restrict__ w2_rel,
                                const float* __restrict__ w2_root,
                                const float* __restrict__ b2,
                                const int* __restrict__ batch,
                                float* __restrict__ out) {
    __shared__ float s_e[HID];
    __shared__ float s_h[HID];
    const int g = blockIdx.x;
    const int c = threadIdx.x;
    s_e[c] = esum[(g << 6) + c];
    s_h[c] = hsum[(g << 6) + c];
    __syncthreads();

    int lo = 0, hi = N_NODES;
    while (lo < hi) { int m = (lo + hi) >> 1; if (batch[m] < g) lo = m + 1; else hi = m; }
    int start = lo;
    hi = N_NODES;
    while (lo < hi) { int m = (lo + hi) >> 1; if (batch[m] < g + 1) lo = m + 1; else hi = m; }
    int cntg = lo - start;

    float acc = (float)cntg * b2[c];
    #pragma unroll
    for (int k = 0; k < HID; ++k) {
        acc += s_e[k] * w2_rel[k * HID + c];
        acc += s_h[k] * w2_root[k * HID + c];
    }
    float denom = cntg > 0 ? (float)cntg : 1.f;
    out[(g << 6) + c] = fmaxf(acc / denom, 0.f);
}

// ---------------------------------------------------------------------------
extern "C" void kernel_launch(void* const* d_in, const int* in_sizes, int n_in,
                              void* d_out, int out_size, void* d_ws, size_t ws_size,
                              hipStream_t stream) {
    const float* x       = (const float*)d_in[0];
    const int*   ei      = (const int*)  d_in[1];
    const int*   batch   = (const int*)  d_in[2];
    const float* w1_rel  = (const float*)d_in[3];
    const float* b1_rel  = (const float*)d_in[4];
    const float* w1_root = (const float*)d_in[5];
    const float* w2_rel  = (const float*)d_in[6];
    const float* b2_rel  = (const float*)d_in[7];
    const float* w2_root = (const float*)d_in[8];
    float* out = (float*)d_out;

    const int* src = ei;
    const int* dst = ei + N_EDGES;

    // ws layout (bytes), peak ~40.5 MB:
    //   [0,       400000)   cnt    N int   (written by build_kernel)
    //   [400000,  465536)   hsum   256*64 f32 (zeroed)
    //   [465536,  531072)   esum   256*64 f32 (zeroed)
    //   [531072,  532636)   gcur   NB int  (zeroed)
    //   [532640, 19732640)  slots  N*48 int (dummy-init via LDS staging)
    //   [19732640,27732720) xb     (N+1)*40 f16  } ebuf (391*4608 uint)
    //   [27732720,40532848) hb     (N+1)*64 f16  } aliases xb; ebuf dead
    //   [19732640,26939552) ebuf (alias)           before pack_x runs
    char* wsb = (char*)d_ws;
    int*    cnt   = (int*)   (wsb);
    float*  hsum  = (float*) (wsb + 400000);
    float*  esum  = (float*) (wsb + 465536);
    int*    gcur  = (int*)   (wsb + 531072);
    int*    slots = (int*)   (wsb + 532640);
    ushort* xb    = (ushort*)(wsb + 19732640);
    ushort* hb    = (ushort*)(wsb + 27732720);
    uint*   ebuf  = (uint*)  (wsb + 19732640);   // alias, see above

    hipMemsetAsync(wsb + 400000, 0, 132636, stream);  // hsum + esum + gcur

    scatter_kernel<<<NBLK, 256, 0, stream>>>(src, dst, gcur, ebuf);
    build_kernel<<<NB, 256, 0, stream>>>(ebuf, gcur, cnt, slots);

    {   // pack x -> f16 [N+1][40]; zero hb dummy row (after ebuf is dead)
        int total = (N_NODES + 1) * F_PAD;
        pack_x_kernel<<<(total + 255) / 256, 256, 0, stream>>>(x, xb, hb);
    }
    {   // layer 1
        int blocks = (N_NODES + 63) / 64;
        layer1_kernel<<<blocks, 256, 0, stream>>>((const uint*)xb, cnt, slots,
                                                  w1_rel, b1_rel, w1_root, batch,
                                                  hb, hsum);
    }
    {   // layer 2: gather + per-graph pooling only
        int blocks = (N_NODES + 63) / 64;
        layer2_kernel<<<blocks, 256, 0, stream>>>((const uint*)hb, cnt, slots,
                                                  batch, esum);
    }
    {   // finalize: esum@w2_rel + hsum@w2_root + bias, mean, relu
        finalize_kernel<<<N_GRAPHS, HID, 0, stream>>>(esum, hsum, w2_rel, w2_root,
                                                      b2_rel, batch, out);
    }
}